// Round 3
// baseline (4825.570 us; speedup 1.0000x reference)
//
#include <hip/hip_runtime.h>

// ---------- types ----------
typedef short v8s __attribute__((ext_vector_type(8)));
typedef float v4f __attribute__((ext_vector_type(4)));

static __device__ __forceinline__ unsigned short f2bf(float x) {
    unsigned u = __builtin_bit_cast(unsigned, x);
    unsigned r = (u + 0x7fffu + ((u >> 16) & 1u)) >> 16;
    return (unsigned short)r;
}

static __device__ __forceinline__ float sigm(float x) {
    return 1.f / (1.f + __expf(-x));
}
static __device__ __forceinline__ float tanh_fast(float x) {
    x = fminf(fmaxf(x, -15.f), 15.f);
    float e = __expf(2.f * x);
    return (e - 1.f) / (e + 1.f);
}

// ---------- elementwise f32 -> bf16 convert ----------
__global__ void cvt_bf16(const float* __restrict__ src, unsigned short* __restrict__ dst, int n) {
    int i = blockIdx.x * 256 + threadIdx.x;
    if (i < n) dst[i] = f2bf(src[i]);
}

// ---------- repack W_hh (f32 [1536][512]) into MFMA B-fragment order ----------
// dst: [96 tiles][16 kf][64 lane][8 i] bf16, per dir.
// B element (n, k): n = tile*16 + (lane&15), k = kf*32 + (lane>>4)*8 + i.
__global__ void repack_whh(const float* __restrict__ src, unsigned short* __restrict__ dst) {
    long e = (long)blockIdx.x * 256 + threadIdx.x;  // < 786432
    int i = e & 7;
    int lane = (e >> 3) & 63;
    int kf = (e >> 9) & 15;
    int T = (int)(e >> 13);  // 0..95
    int gcol = T * 16 + (lane & 15);
    int k = kf * 32 + (lane >> 4) * 8 + i;
    dst[e] = f2bf(src[(long)gcol * 512 + k]);
}

// ---------- zero the h-share buffers + team counters ----------
__global__ void init_sync(unsigned int* __restrict__ p, int n) {
    int i = blockIdx.x * 256 + threadIdx.x;
    if (i < n) p[i] = 0;
}

// ---------- build X = concat(embed_table[slot_ids], value_embeds) as bf16 [16384][1024] ----------
__global__ void build_x(const int* __restrict__ slot_ids,
                        const float* __restrict__ value_embeds,
                        const float* __restrict__ embed_table,
                        unsigned short* __restrict__ X) {
    int r = blockIdx.x;           // r = b*64 + s
    int t = threadIdx.x;          // 256 threads
    int id = slot_ids[r];
    X[(long)r * 1024 + t] = f2bf(embed_table[id * 256 + t]);
#pragma unroll
    for (int i = 0; i < 3; i++) {
        int c = t + i * 256;
        X[(long)r * 1024 + 256 + c] = f2bf(value_embeds[(long)r * 768 + c]);
    }
}

// ---------- bf16 MFMA GEMM: C[M][N] = A[M][K] * Bt[N][K]^T ----------
template <int EPI>
__global__ __launch_bounds__(256) void gemm_bt(const unsigned short* __restrict__ A,
                                               const unsigned short* __restrict__ Bt,
                                               float* __restrict__ C,
                                               int M, int N, int K) {
    const int LDT = 72;
    __shared__ unsigned short As[128 * 72];
    __shared__ unsigned short Bs[128 * 72];
    int tid = threadIdx.x;
    int lane = tid & 63;
    int wave = tid >> 6;
    int gm0 = blockIdx.y * 128;
    int gn0 = blockIdx.x * 128;
    int wm0 = (wave >> 1) * 64;
    int wn0 = (wave & 1) * 64;
    int q = lane >> 4;
    int l16 = lane & 15;

    v4f acc[4][4];
#pragma unroll
    for (int i = 0; i < 4; i++)
#pragma unroll
        for (int j = 0; j < 4; j++) acc[i][j] = v4f{0.f, 0.f, 0.f, 0.f};

    for (int k0 = 0; k0 < K; k0 += 64) {
#pragma unroll
        for (int l = tid; l < 1024; l += 256) {
            int row = l >> 3;
            int col = (l & 7) * 8;
            *(v8s*)&As[row * LDT + col] = *(const v8s*)&A[(long)(gm0 + row) * K + k0 + col];
            *(v8s*)&Bs[row * LDT + col] = *(const v8s*)&Bt[(long)(gn0 + row) * K + k0 + col];
        }
        __syncthreads();
#pragma unroll
        for (int kf = 0; kf < 2; kf++) {
            v8s af[4], bfr[4];
#pragma unroll
            for (int mi = 0; mi < 4; mi++)
                af[mi] = *(const v8s*)&As[(wm0 + mi * 16 + l16) * LDT + kf * 32 + q * 8];
#pragma unroll
            for (int ni = 0; ni < 4; ni++)
                bfr[ni] = *(const v8s*)&Bs[(wn0 + ni * 16 + l16) * LDT + kf * 32 + q * 8];
#pragma unroll
            for (int mi = 0; mi < 4; mi++)
#pragma unroll
                for (int ni = 0; ni < 4; ni++)
                    acc[mi][ni] = __builtin_amdgcn_mfma_f32_16x16x32_bf16(af[mi], bfr[ni], acc[mi][ni], 0, 0, 0);
        }
        __syncthreads();
    }

#pragma unroll
    for (int mi = 0; mi < 4; mi++)
#pragma unroll
        for (int ni = 0; ni < 4; ni++) {
            int col = gn0 + wn0 + ni * 16 + l16;
#pragma unroll
            for (int r = 0; r < 4; r++) {
                int row = gm0 + wm0 + mi * 16 + q * 4 + r;
                float v = acc[mi][ni][r];
                if (EPI == 0) {
                    C[(long)row * N + col] = v;
                } else {
                    int d = (col >= 1536) ? 1 : 0;
                    int g = col - d * 1536;
                    int b = row >> 6, s = row & 63;
                    C[(((long)(d * 64 + s)) * 256 + b) * 1536 + g] = v;
                }
            }
        }
}

// ---------- GRU recurrence, W-in-registers + team barrier ----------
// 256 blocks x 768 threads (12 waves). team = blockIdx>>3 (dir*16+bg), cg = blockIdx&7.
// Block owns 64 h-cols (12 gate tiles of 16 cols; wave w: gate g=w>>2, subtile c=w&3).
// W fragments persist in VGPRs (64/lane). Per step: load h_prev [16x512] bf16 from the
// team's global h-share (A-fragment layout), 16 MFMA/wave, gate-combine via LDS
// (waves 0-3), write h slice (double-buffered), device-scope 8-block team barrier.
__global__ __launch_bounds__(768) void gru_rec(const float* __restrict__ gi,           // [2][64][256][1536]
                                               const unsigned short* __restrict__ Wpk, // [2][96][16][64][8]
                                               const float* __restrict__ bih_f,
                                               const float* __restrict__ bhh_f,
                                               const float* __restrict__ bih_b,
                                               const float* __restrict__ bhh_b,
                                               unsigned short* __restrict__ hout,      // [256][64][1024]
                                               unsigned short* __restrict__ hshare,    // [32][2][8192]
                                               unsigned int* __restrict__ ctr) {       // [32][16]
    __shared__ float gates[12][16][17];
    int tid = threadIdx.x;
    int lane = tid & 63;
    int wave = tid >> 6;          // 0..11
    int q = lane >> 4, l16 = lane & 15;
    int blk = blockIdx.x;
    int team = blk >> 3;          // 0..31
    int cg = blk & 7;
    int d = team >> 4;
    int b0 = (team & 15) * 16;
    int g = wave >> 2;            // gate 0..2
    int c = wave & 3;             // col subtile
    const float* giD = gi + (long)d * 64 * 256 * 1536;

    // persistent W fragments for this wave's tile
    int tile = g * 32 + cg * 4 + c;
    const unsigned short* Wt = Wpk + ((long)d * 96 + tile) * 8192 + lane * 8;
    v8s bw[16];
#pragma unroll
    for (int kf = 0; kf < 16; kf++) bw[kf] = *(const v8s*)&Wt[kf * 512];

    unsigned short* hsA = hshare + (long)team * 2 * 8192;
    unsigned int* myctr = ctr + team * 16;

    // combiner (waves 0-3) setup: col j = cg*64 + wave*16 + l16
    float bi[3], bh[3];
    float hreg[4] = {0.f, 0.f, 0.f, 0.f};
    int jcol = cg * 64 + wave * 16 + l16;
    if (wave < 4) {
        const float* bihp = d ? bih_b : bih_f;
        const float* bhhp = d ? bhh_b : bhh_f;
#pragma unroll
        for (int gg = 0; gg < 3; gg++) {
            bi[gg] = bihp[gg * 512 + jcol];
            bh[gg] = bhhp[gg * 512 + jcol];
        }
    }

    for (int t = 0; t < 64; t++) {
        int s = d ? (63 - t) : t;
        const unsigned short* prev = hsA + ((t + 1) & 1) * 8192;
        unsigned short* cur = hsA + (t & 1) * 8192;

        // combiner gi prefetch (independent of h)
        float gir[3][4];
        if (wave < 4) {
            long base = ((long)s * 256 + b0) * 1536;
#pragma unroll
            for (int gg = 0; gg < 3; gg++)
#pragma unroll
                for (int r = 0; r < 4; r++)
                    gir[gg][r] = giD[base + (long)(q * 4 + r) * 1536 + gg * 512 + jcol];
        }

        // h_prev @ W_tile : 16 MFMA, two 8-kf halves (two acc chains)
        v4f accA = v4f{0.f, 0.f, 0.f, 0.f};
        v4f accB = v4f{0.f, 0.f, 0.f, 0.f};
        {
            v8s af[8];
#pragma unroll
            for (int k = 0; k < 8; k++) af[k] = *(const v8s*)&prev[(k * 64 + lane) * 8];
#pragma unroll
            for (int k = 0; k < 8; k++)
                accA = __builtin_amdgcn_mfma_f32_16x16x32_bf16(af[k], bw[k], accA, 0, 0, 0);
#pragma unroll
            for (int k = 0; k < 8; k++) af[k] = *(const v8s*)&prev[((8 + k) * 64 + lane) * 8];
#pragma unroll
            for (int k = 0; k < 8; k++)
                accB = __builtin_amdgcn_mfma_f32_16x16x32_bf16(af[k], bw[8 + k], accB, 0, 0, 0);
        }
#pragma unroll
        for (int r = 0; r < 4; r++) gates[wave][q * 4 + r][l16] = accA[r] + accB[r];
        __syncthreads();

        if (wave < 4) {
#pragma unroll
            for (int r = 0; r < 4; r++) {
                int m = q * 4 + r;
                float rr = sigm(gir[0][r] + bi[0] + gates[wave][m][l16] + bh[0]);
                float zz = sigm(gir[1][r] + bi[1] + gates[4 + wave][m][l16] + bh[1]);
                float nn = tanh_fast(gir[2][r] + bi[2] + rr * (gates[8 + wave][m][l16] + bh[2]));
                float hn = (1.f - zz) * nn + zz * hreg[r];
                hreg[r] = hn;
                unsigned short hv = f2bf(hn);
                // h-share in A-fragment layout: [kf][qq*16+m][i]
                int kf = cg * 2 + (wave >> 1);
                int qq = (wave & 1) * 2 + (l16 >> 3);
                int ii = l16 & 7;
                cur[kf * 512 + qq * 128 + m * 8 + ii] = hv;
                hout[((long)(b0 + m) * 64 + s) * 1024 + d * 512 + jcol] = hv;
            }
        }
        __syncthreads();
        if (t < 63) {
            if (tid == 0)
                __hip_atomic_fetch_add(myctr, 1u, __ATOMIC_RELEASE, __HIP_MEMORY_SCOPE_AGENT);
            unsigned int tgt = 8u * (unsigned)(t + 1);
            while (__hip_atomic_load(myctr, __ATOMIC_ACQUIRE, __HIP_MEMORY_SCOPE_AGENT) < tgt)
                __builtin_amdgcn_s_sleep(2);
        }
    }
}

extern "C" void kernel_launch(void* const* d_in, const int* in_sizes, int n_in,
                              void* d_out, int out_size, void* d_ws, size_t ws_size,
                              hipStream_t stream) {
    const int* slot_ids = (const int*)d_in[0];
    const float* value_embeds = (const float*)d_in[1];
    const float* embed_table = (const float*)d_in[2];
    const float* W_ih_f = (const float*)d_in[3];
    const float* W_hh_f = (const float*)d_in[4];
    const float* b_ih_f = (const float*)d_in[5];
    const float* b_hh_f = (const float*)d_in[6];
    const float* W_ih_b = (const float*)d_in[7];
    const float* W_hh_b = (const float*)d_in[8];
    const float* b_ih_b = (const float*)d_in[9];
    const float* b_hh_b = (const float*)d_in[10];
    const float* W_proj = (const float*)d_in[11];
    float* out = (float*)d_out;
    char* ws = (char*)d_ws;

    // workspace layout (bytes)
    unsigned short* X = (unsigned short*)(ws + 0);              // 16384x1024 bf16 = 33,554,432
    float* gi = (float*)(ws + 33554432);                        // 2x64x256x1536 f32 = 201,326,592
    unsigned short* Wstk = (unsigned short*)(ws + 234881024);   // 3072x1024 bf16 = 6,291,456 (dead after gemm1)
    unsigned short* Wpk = (unsigned short*)(ws + 241172480);    // 2x96x16x64x8 bf16 = 3,145,728
    unsigned short* Wp = (unsigned short*)(ws + 244318208);     // 512x1024 bf16 = 1,048,576
    unsigned short* hout = X;  // alias: X is dead after gemm1
    // h-share + counters alias the (dead-after-gemm1) Wstk region
    unsigned short* hshare = Wstk;                              // 32*2*8192 bf16 = 1,048,576 B
    unsigned int* ctr = (unsigned int*)(ws + 234881024 + 1048576);  // 32*16 uint = 2 KB

    cvt_bf16<<<6144, 256, 0, stream>>>(W_ih_f, Wstk, 1536 * 1024);
    cvt_bf16<<<6144, 256, 0, stream>>>(W_ih_b, Wstk + 1536 * 1024, 1536 * 1024);
    repack_whh<<<3072, 256, 0, stream>>>(W_hh_f, Wpk);
    repack_whh<<<3072, 256, 0, stream>>>(W_hh_b, Wpk + 786432);
    cvt_bf16<<<2048, 256, 0, stream>>>(W_proj, Wp, 512 * 1024);
    build_x<<<16384, 256, 0, stream>>>(slot_ids, value_embeds, embed_table, X);

    // gi = X @ [Wih_f; Wih_b]^T   (M=16384, N=3072, K=1024)
    gemm_bt<1><<<dim3(24, 128), 256, 0, stream>>>(X, Wstk, gi, 16384, 3072, 1024);

    // zero h-share + team counters (must run AFTER gemm1: aliases Wstk)
    init_sync<<<1027, 256, 0, stream>>>((unsigned int*)hshare, (1048576 + 2048) / 4);

    // recurrence (both directions), persistent-W team kernel
    gru_rec<<<256, 768, 0, stream>>>(gi, Wpk, b_ih_f, b_hh_f, b_ih_b, b_hh_b, hout, hshare, ctr);

    // out = hcat @ W_proj^T   (M=16384, N=512, K=1024)
    gemm_bt<0><<<dim3(4, 128), 256, 0, stream>>>(hout, Wp, out, 16384, 512, 1024);
}

// Round 5
// 3128.382 us; speedup vs baseline: 1.5425x; 1.5425x over previous
//
#include <hip/hip_runtime.h>

// ---------- types ----------
typedef short v8s __attribute__((ext_vector_type(8)));
typedef float v4f __attribute__((ext_vector_type(4)));

static __device__ __forceinline__ unsigned short f2bf(float x) {
    unsigned u = __builtin_bit_cast(unsigned, x);
    unsigned r = (u + 0x7fffu + ((u >> 16) & 1u)) >> 16;
    return (unsigned short)r;
}

static __device__ __forceinline__ float sigm(float x) {
    return 1.f / (1.f + __expf(-x));
}
static __device__ __forceinline__ float tanh_fast(float x) {
    x = fminf(fmaxf(x, -15.f), 15.f);
    float e = __expf(2.f * x);
    return (e - 1.f) / (e + 1.f);
}

// ---------- elementwise f32 -> bf16 convert ----------
__global__ void cvt_bf16(const float* __restrict__ src, unsigned short* __restrict__ dst, int n) {
    int i = blockIdx.x * 256 + threadIdx.x;
    if (i < n) dst[i] = f2bf(src[i]);
}

// ---------- repack W_hh (f32 [1536][512]) into MFMA B-fragment order ----------
// dst: [96 tiles][16 kf][64 lane][8 i] bf16, per dir.
// B element (n, k): n = tile*16 + (lane&15), k = kf*32 + (lane>>4)*8 + i.
__global__ void repack_whh(const float* __restrict__ src, unsigned short* __restrict__ dst) {
    long e = (long)blockIdx.x * 256 + threadIdx.x;  // < 786432
    int i = e & 7;
    int lane = (e >> 3) & 63;
    int kf = (e >> 9) & 15;
    int T = (int)(e >> 13);  // 0..95
    int gcol = T * 16 + (lane & 15);
    int k = kf * 32 + (lane >> 4) * 8 + i;
    dst[e] = f2bf(src[(long)gcol * 512 + k]);
}

// ---------- build X = concat(embed_table[slot_ids], value_embeds) as bf16 [16384][1024] ----------
__global__ void build_x(const int* __restrict__ slot_ids,
                        const float* __restrict__ value_embeds,
                        const float* __restrict__ embed_table,
                        unsigned short* __restrict__ X) {
    int r = blockIdx.x;           // r = b*64 + s
    int t = threadIdx.x;          // 256 threads
    int id = slot_ids[r];
    X[(long)r * 1024 + t] = f2bf(embed_table[id * 256 + t]);
#pragma unroll
    for (int i = 0; i < 3; i++) {
        int c = t + i * 256;
        X[(long)r * 1024 + 256 + c] = f2bf(value_embeds[(long)r * 768 + c]);
    }
}

// ---------- bf16 MFMA GEMM: C[M][N] = A[M][K] * Bt[N][K]^T ----------
// EPI=0: plain f32 store C[row*N+col]
// EPI=1: scatter into gi packed per consumer wave:
//   [d][s][bgrp 16][wave 16][cc 2][g 3][lane 64][r 4] f32
template <int EPI>
__global__ __launch_bounds__(256) void gemm_bt(const unsigned short* __restrict__ A,
                                               const unsigned short* __restrict__ Bt,
                                               float* __restrict__ C,
                                               int M, int N, int K) {
    const int LDT = 72;
    __shared__ unsigned short As[128 * 72];
    __shared__ unsigned short Bs[128 * 72];
    int tid = threadIdx.x;
    int lane = tid & 63;
    int wave = tid >> 6;
    int gm0 = blockIdx.y * 128;
    int gn0 = blockIdx.x * 128;
    int wm0 = (wave >> 1) * 64;
    int wn0 = (wave & 1) * 64;
    int q = lane >> 4;
    int l16 = lane & 15;

    v4f acc[4][4];
#pragma unroll
    for (int i = 0; i < 4; i++)
#pragma unroll
        for (int j = 0; j < 4; j++) acc[i][j] = v4f{0.f, 0.f, 0.f, 0.f};

    for (int k0 = 0; k0 < K; k0 += 64) {
#pragma unroll
        for (int l = tid; l < 1024; l += 256) {
            int row = l >> 3;
            int col = (l & 7) * 8;
            *(v8s*)&As[row * LDT + col] = *(const v8s*)&A[(long)(gm0 + row) * K + k0 + col];
            *(v8s*)&Bs[row * LDT + col] = *(const v8s*)&Bt[(long)(gn0 + row) * K + k0 + col];
        }
        __syncthreads();
#pragma unroll
        for (int kf = 0; kf < 2; kf++) {
            v8s af[4], bfr[4];
#pragma unroll
            for (int mi = 0; mi < 4; mi++)
                af[mi] = *(const v8s*)&As[(wm0 + mi * 16 + l16) * LDT + kf * 32 + q * 8];
#pragma unroll
            for (int ni = 0; ni < 4; ni++)
                bfr[ni] = *(const v8s*)&Bs[(wn0 + ni * 16 + l16) * LDT + kf * 32 + q * 8];
#pragma unroll
            for (int mi = 0; mi < 4; mi++)
#pragma unroll
                for (int ni = 0; ni < 4; ni++)
                    acc[mi][ni] = __builtin_amdgcn_mfma_f32_16x16x32_bf16(af[mi], bfr[ni], acc[mi][ni], 0, 0, 0);
        }
        __syncthreads();
    }

#pragma unroll
    for (int mi = 0; mi < 4; mi++)
#pragma unroll
        for (int ni = 0; ni < 4; ni++) {
            int col = gn0 + wn0 + ni * 16 + l16;
#pragma unroll
            for (int r = 0; r < 4; r++) {
                int row = gm0 + wm0 + mi * 16 + q * 4 + r;
                float v = acc[mi][ni][r];
                if (EPI == 0) {
                    C[(long)row * N + col] = v;
                } else {
                    int d = (col >= 1536) ? 1 : 0;
                    int gcol = col - d * 1536;
                    int g = gcol >> 9;
                    int j = gcol & 511;
                    int wv = j >> 5, cc = (j >> 4) & 1, l16c = j & 15;
                    int b = row >> 6, s = row & 63;
                    int bgrp = b >> 4, brow = b & 15;
                    int qc = brow >> 2, rc = brow & 3;
                    long idx = ((((((long)(d * 64 + s) * 16 + bgrp) * 16 + wv) * 2 + cc) * 3 + g) * 64 +
                                (qc * 16 + l16c)) * 4 + rc;
                    C[idx] = v;
                }
            }
        }
}

// ---------- GRU recurrence: zero inter-block sync, W streamed from (L2-resident) cache ----
// 32 blocks x 1024 threads (16 waves). blockIdx.x = dir*16 + batch_group (16 rows).
// Wave w owns h-cols [w*32, w*32+32) for ALL 3 gates (6 B-tiles) -> in-register combine.
// gi is pre-packed per (block, wave): 6 coalesced v4f loads/step, nontemporal (keeps W in L2).
// h double-buffered in LDS; ONE __syncthreads per step.
__global__ __launch_bounds__(1024) void gru_rec(const float* __restrict__ gi,           // packed, see gemm EPI=1
                                                const unsigned short* __restrict__ Wpk, // [2][96][16][64][8]
                                                const float* __restrict__ bih_f,
                                                const float* __restrict__ bhh_f,
                                                const float* __restrict__ bih_b,
                                                const float* __restrict__ bhh_b,
                                                unsigned short* __restrict__ hout) {    // [256][64][1024]
    const int HB_LD = 520;  // padded row stride (shorts)
    __shared__ unsigned short hb[2][16 * HB_LD];
    int tid = threadIdx.x;
    int lane = tid & 63;
    int wave = tid >> 6;          // 0..15
    int q = lane >> 4, l16 = lane & 15;
    int d = blockIdx.x >> 4;
    int bgrp = blockIdx.x & 15;
    int b0 = bgrp * 16;

    // W tile base (per dir) + per-(cc,g) fragment pointers; tile = g*32 + wave*2 + cc
    const unsigned short* wp[2][3];
#pragma unroll
    for (int cc = 0; cc < 2; cc++)
#pragma unroll
        for (int g = 0; g < 3; g++)
            wp[cc][g] = Wpk + ((long)d * 96 + g * 32 + wave * 2 + cc) * 8192 + lane * 8;

    // per-lane biases for owned columns j = wave*32 + cc*16 + l16
    float bi[2][3], bh[2][3];
    {
        const float* bihp = d ? bih_b : bih_f;
        const float* bhhp = d ? bhh_b : bhh_f;
#pragma unroll
        for (int cc = 0; cc < 2; cc++) {
            int j = wave * 32 + cc * 16 + l16;
#pragma unroll
            for (int g = 0; g < 3; g++) {
                bi[cc][g] = bihp[g * 512 + j];
                bh[cc][g] = bhhp[g * 512 + j];
            }
        }
    }

    float hreg[2][4];
#pragma unroll
    for (int cc = 0; cc < 2; cc++)
#pragma unroll
        for (int r = 0; r < 4; r++) hreg[cc][r] = 0.f;

    // zero both h buffers (h0 = 0)
    unsigned short* hbf = &hb[0][0];
    for (int i = tid; i < 2 * 16 * HB_LD; i += 1024) hbf[i] = 0;
    __syncthreads();

    // gi base for this (d, bgrp, wave); stride over s = 16*16*2*3*256 floats
    const long s_stride = (long)16 * 16 * 2 * 3 * 256;
    const float* gbase = gi + (((long)d * 64 * 16 + bgrp) * 16 + wave) * 2 * 3 * 256 + lane * 4;

    for (int t = 0; t < 64; t++) {
        int s = d ? (63 - t) : t;
        const unsigned short* prev = hb[(t + 1) & 1];
        unsigned short* cur = hb[t & 1];

        // gi: 6 coalesced v4f nontemporal loads (read-once stream; don't pollute L2)
        v4f gir[2][3];
        {
            const float* gp = gbase + (long)s * s_stride;
#pragma unroll
            for (int cc = 0; cc < 2; cc++)
#pragma unroll
                for (int g = 0; g < 3; g++) {
                    const v4f* p = (const v4f*)(gp + (cc * 3 + g) * 256);
                    gir[cc][g] = __builtin_nontemporal_load(p);
                }
        }

        // h_prev @ W : 96 MFMA per wave, 6 independent acc chains
        v4f acc[2][3];
#pragma unroll
        for (int cc = 0; cc < 2; cc++)
#pragma unroll
            for (int g = 0; g < 3; g++) acc[cc][g] = v4f{0.f, 0.f, 0.f, 0.f};

#pragma unroll
        for (int kc = 0; kc < 4; kc++) {
            v8s af[4];
#pragma unroll
            for (int k = 0; k < 4; k++)
                af[k] = *(const v8s*)&prev[l16 * HB_LD + (kc * 4 + k) * 32 + q * 8];
#pragma unroll
            for (int k = 0; k < 4; k++) {
                int kf = kc * 4 + k;
#pragma unroll
                for (int cc = 0; cc < 2; cc++)
#pragma unroll
                    for (int g = 0; g < 3; g++) {
                        v8s b = *(const v8s*)&wp[cc][g][(long)kf * 512];
                        acc[cc][g] = __builtin_amdgcn_mfma_f32_16x16x32_bf16(af[k], b, acc[cc][g], 0, 0, 0);
                    }
            }
        }

        // in-register gate combine; write h to LDS (next step) + global hout
#pragma unroll
        for (int cc = 0; cc < 2; cc++) {
            int j = wave * 32 + cc * 16 + l16;
#pragma unroll
            for (int r = 0; r < 4; r++) {
                int m = q * 4 + r;
                float rr = sigm(gir[cc][0][r] + bi[cc][0] + acc[cc][0][r] + bh[cc][0]);
                float zz = sigm(gir[cc][1][r] + bi[cc][1] + acc[cc][1][r] + bh[cc][1]);
                float nn = tanh_fast(gir[cc][2][r] + bi[cc][2] + rr * (acc[cc][2][r] + bh[cc][2]));
                float hn = (1.f - zz) * nn + zz * hreg[cc][r];
                hreg[cc][r] = hn;
                unsigned short hv = f2bf(hn);
                cur[m * HB_LD + j] = hv;
                hout[((long)(b0 + m) * 64 + s) * 1024 + d * 512 + j] = hv;
            }
        }
        __syncthreads();
    }
}

extern "C" void kernel_launch(void* const* d_in, const int* in_sizes, int n_in,
                              void* d_out, int out_size, void* d_ws, size_t ws_size,
                              hipStream_t stream) {
    const int* slot_ids = (const int*)d_in[0];
    const float* value_embeds = (const float*)d_in[1];
    const float* embed_table = (const float*)d_in[2];
    const float* W_ih_f = (const float*)d_in[3];
    const float* W_hh_f = (const float*)d_in[4];
    const float* b_ih_f = (const float*)d_in[5];
    const float* b_hh_f = (const float*)d_in[6];
    const float* W_ih_b = (const float*)d_in[7];
    const float* W_hh_b = (const float*)d_in[8];
    const float* b_ih_b = (const float*)d_in[9];
    const float* b_hh_b = (const float*)d_in[10];
    const float* W_proj = (const float*)d_in[11];
    float* out = (float*)d_out;
    char* ws = (char*)d_ws;

    // workspace layout (bytes)
    unsigned short* X = (unsigned short*)(ws + 0);              // 16384x1024 bf16 = 33,554,432
    float* gi = (float*)(ws + 33554432);                        // 50,331,648 f32 = 201,326,592
    unsigned short* Wstk = (unsigned short*)(ws + 234881024);   // 3072x1024 bf16 = 6,291,456 (dead after gemm1)
    unsigned short* Wpk = (unsigned short*)(ws + 241172480);    // 2x96x16x64x8 bf16 = 3,145,728
    unsigned short* Wp = (unsigned short*)(ws + 244318208);     // 512x1024 bf16 = 1,048,576
    unsigned short* hout = X;  // alias: X is dead after gemm1

    cvt_bf16<<<6144, 256, 0, stream>>>(W_ih_f, Wstk, 1536 * 1024);
    cvt_bf16<<<6144, 256, 0, stream>>>(W_ih_b, Wstk + 1536 * 1024, 1536 * 1024);
    repack_whh<<<3072, 256, 0, stream>>>(W_hh_f, Wpk);
    repack_whh<<<3072, 256, 0, stream>>>(W_hh_b, Wpk + 786432);
    cvt_bf16<<<2048, 256, 0, stream>>>(W_proj, Wp, 512 * 1024);
    build_x<<<16384, 256, 0, stream>>>(slot_ids, value_embeds, embed_table, X);

    // gi = X @ [Wih_f; Wih_b]^T  (M=16384, N=3072, K=1024), epilogue scatters packed
    gemm_bt<1><<<dim3(24, 128), 256, 0, stream>>>(X, Wstk, gi, 16384, 3072, 1024);

    // recurrence: 32 self-contained blocks, W streamed from L2
    gru_rec<<<32, 1024, 0, stream>>>(gi, Wpk, b_ih_f, b_hh_f, b_ih_b, b_hh_b, hout);

    // out = hcat @ W_proj^T   (M=16384, N=512, K=1024)
    gemm_bt<0><<<dim3(4, 128), 256, 0, stream>>>(hout, Wp, out, 16384, 512, 1024);
}

// Round 6
// 1373.098 us; speedup vs baseline: 3.5144x; 2.2783x over previous
//
#include <hip/hip_runtime.h>

// ---------- types ----------
typedef short v8s __attribute__((ext_vector_type(8)));
typedef float v4f __attribute__((ext_vector_type(4)));

static __device__ __forceinline__ unsigned short f2bf(float x) {
    unsigned u = __builtin_bit_cast(unsigned, x);
    unsigned r = (u + 0x7fffu + ((u >> 16) & 1u)) >> 16;
    return (unsigned short)r;
}

static __device__ __forceinline__ float sigm(float x) {
    return 1.f / (1.f + __expf(-x));
}
static __device__ __forceinline__ float tanh_fast(float x) {
    x = fminf(fmaxf(x, -15.f), 15.f);
    float e = __expf(2.f * x);
    return (e - 1.f) / (e + 1.f);
}

// ---------- elementwise f32 -> bf16 convert ----------
__global__ void cvt_bf16(const float* __restrict__ src, unsigned short* __restrict__ dst, int n) {
    int i = blockIdx.x * 256 + threadIdx.x;
    if (i < n) dst[i] = f2bf(src[i]);
}

// ---------- repack W_hh (f32 [1536][512]) into MFMA B-fragment order ----------
// dst: [96 tiles][16 kf][64 lane][8 i] bf16, per dir.
__global__ void repack_whh(const float* __restrict__ src, unsigned short* __restrict__ dst) {
    long e = (long)blockIdx.x * 256 + threadIdx.x;  // < 786432
    int i = e & 7;
    int lane = (e >> 3) & 63;
    int kf = (e >> 9) & 15;
    int T = (int)(e >> 13);  // 0..95
    int gcol = T * 16 + (lane & 15);
    int k = kf * 32 + (lane >> 4) * 8 + i;
    dst[e] = f2bf(src[(long)gcol * 512 + k]);
}

// ---------- zero team flags (every launch, incl. graph replays) ----------
__global__ void init_flags(unsigned int* __restrict__ p) {
    p[threadIdx.x] = 0;
}

// ---------- build X = concat(embed_table[slot_ids], value_embeds) as bf16 [16384][1024] ----------
__global__ void build_x(const int* __restrict__ slot_ids,
                        const float* __restrict__ value_embeds,
                        const float* __restrict__ embed_table,
                        unsigned short* __restrict__ X) {
    int r = blockIdx.x;           // r = b*64 + s
    int t = threadIdx.x;          // 256 threads
    int id = slot_ids[r];
    X[(long)r * 1024 + t] = f2bf(embed_table[id * 256 + t]);
#pragma unroll
    for (int i = 0; i < 3; i++) {
        int c = t + i * 256;
        X[(long)r * 1024 + 256 + c] = f2bf(value_embeds[(long)r * 768 + c]);
    }
}

// ---------- bf16 MFMA GEMM: C[M][N] = A[M][K] * Bt[N][K]^T ----------
// EPI=0: plain f32 store C[row*N+col]
// EPI=1: scatter gi packed for gru_rec consumers:
//   [d][s][bg 8][cb 16][wave 4][g 3][lane 64][r 4] f32
template <int EPI>
__global__ __launch_bounds__(256) void gemm_bt(const unsigned short* __restrict__ A,
                                               const unsigned short* __restrict__ Bt,
                                               float* __restrict__ C,
                                               int M, int N, int K) {
    const int LDT = 72;
    __shared__ unsigned short As[128 * 72];
    __shared__ unsigned short Bs[128 * 72];
    int tid = threadIdx.x;
    int lane = tid & 63;
    int wave = tid >> 6;
    int gm0 = blockIdx.y * 128;
    int gn0 = blockIdx.x * 128;
    int wm0 = (wave >> 1) * 64;
    int wn0 = (wave & 1) * 64;
    int q = lane >> 4;
    int l16 = lane & 15;

    v4f acc[4][4];
#pragma unroll
    for (int i = 0; i < 4; i++)
#pragma unroll
        for (int j = 0; j < 4; j++) acc[i][j] = v4f{0.f, 0.f, 0.f, 0.f};

    for (int k0 = 0; k0 < K; k0 += 64) {
#pragma unroll
        for (int l = tid; l < 1024; l += 256) {
            int row = l >> 3;
            int col = (l & 7) * 8;
            *(v8s*)&As[row * LDT + col] = *(const v8s*)&A[(long)(gm0 + row) * K + k0 + col];
            *(v8s*)&Bs[row * LDT + col] = *(const v8s*)&Bt[(long)(gn0 + row) * K + k0 + col];
        }
        __syncthreads();
#pragma unroll
        for (int kf = 0; kf < 2; kf++) {
            v8s af[4], bfr[4];
#pragma unroll
            for (int mi = 0; mi < 4; mi++)
                af[mi] = *(const v8s*)&As[(wm0 + mi * 16 + l16) * LDT + kf * 32 + q * 8];
#pragma unroll
            for (int ni = 0; ni < 4; ni++)
                bfr[ni] = *(const v8s*)&Bs[(wn0 + ni * 16 + l16) * LDT + kf * 32 + q * 8];
#pragma unroll
            for (int mi = 0; mi < 4; mi++)
#pragma unroll
                for (int ni = 0; ni < 4; ni++)
                    acc[mi][ni] = __builtin_amdgcn_mfma_f32_16x16x32_bf16(af[mi], bfr[ni], acc[mi][ni], 0, 0, 0);
        }
        __syncthreads();
    }

#pragma unroll
    for (int mi = 0; mi < 4; mi++)
#pragma unroll
        for (int ni = 0; ni < 4; ni++) {
            int col = gn0 + wn0 + ni * 16 + l16;
#pragma unroll
            for (int r = 0; r < 4; r++) {
                int row = gm0 + wm0 + mi * 16 + q * 4 + r;
                float v = acc[mi][ni][r];
                if (EPI == 0) {
                    C[(long)row * N + col] = v;
                } else {
                    int dd = (col >= 1536) ? 1 : 0;
                    int gcol = col - dd * 1536;
                    int g = gcol >> 9;
                    int jj = gcol & 511;
                    int cb = jj >> 5;
                    int jc = jj & 31;
                    int jh = jc >> 4;
                    int l16c = jc & 15;
                    int b = row >> 6, s = row & 63;
                    int bg = b >> 5, brow = b & 31;
                    int rgc = brow >> 4, m = brow & 15;
                    int qc = m >> 2, rc = m & 3;
                    int wv = rgc * 2 + jh;
                    long idx = (((((long)(dd * 64 + s) * 8 + bg) * 16 + cb) * 4 + wv) * 3 + g) * 256 +
                               (qc * 16 + l16c) * 4 + rc;
                    C[idx] = v;
                }
            }
        }
}

// ---------- GRU recurrence: W in LDS, column-split teams, per-slot flag sync ----------
// 256 blocks x 256 threads (1 block/CU). blk = d*128 + bg*16 + cb.
// team = (d,bg): 16 blocks splitting 512 h-cols (32 each). Block LDS: its W slice
// (96 gate-cols x 512 = 96KB, B-frag order) + staged team h (32 rows x 512, 32.5KB).
// Per step: poll 16 flags (relaxed agent) -> stage h_{t-1} from global share (sc1) ->
// 48 MFMA/wave (3 gates, in-reg combine) -> write 2KB h slice (sc1, shfl-paired) ->
// flag=t+1 after __syncthreads (vmcnt drain). Max skew 1 step; 2 buffers by parity.
extern __shared__ __align__(16) char smem[];
__global__ __launch_bounds__(256) void gru_rec(const float* __restrict__ gi,           // packed, see EPI=1
                                               const unsigned short* __restrict__ Wpk, // [2][96][16][64][8]
                                               const float* __restrict__ bih_f,
                                               const float* __restrict__ bhh_f,
                                               const float* __restrict__ bih_b,
                                               const float* __restrict__ bhh_b,
                                               unsigned short* __restrict__ hout,      // [256][64][1024]
                                               unsigned int* __restrict__ hshd,        // [16][2][8192] dwords
                                               unsigned int* __restrict__ flags) {     // [16][16]
    unsigned short* Wl = (unsigned short*)smem;            // [6 slots][16 kf][64 lane][8]
    char* hl = smem + 98304;                               // [32 rows][520 shorts] (1040 B rows)
    int tid = threadIdx.x;
    int lane = tid & 63;
    int wave = tid >> 6;          // 0..3
    int q = lane >> 4, l16 = lane & 15;
    int blk = blockIdx.x;
    int d = blk >> 7;
    int bg = (blk >> 4) & 7;
    int cb = blk & 15;
    int team = d * 8 + bg;
    int rg = wave >> 1, jh = wave & 1;
    int j = cb * 32 + jh * 16 + l16;   // owned h-col

    // load W slice into LDS: slot = g*2+jh order; 6 tiles x 1024 chunks of 16B
    for (int i = tid; i < 6 * 1024; i += 256) {
        int tile = i >> 10;
        int off = i & 1023;
        int gt = (tile >> 1) * 32 + cb * 2 + (tile & 1);
        *(v8s*)&Wl[(long)tile * 8192 + off * 8] = *(const v8s*)&Wpk[((long)d * 96 + gt) * 8192 + off * 8];
    }
    // zero staged h (h0 = 0)
    for (int i = tid; i < 8320; i += 256) ((unsigned int*)hl)[i] = 0;

    float bi[3], bh[3];
    {
        const float* bihp = d ? bih_b : bih_f;
        const float* bhhp = d ? bhh_b : bhh_f;
#pragma unroll
        for (int g = 0; g < 3; g++) {
            bi[g] = bihp[g * 512 + j];
            bh[g] = bhhp[g * 512 + j];
        }
    }
    float hreg[4] = {0.f, 0.f, 0.f, 0.f};

    unsigned int* myflags = flags + team * 16;
    unsigned int* hsteam = hshd + (long)team * 2 * 8192;
    __syncthreads();

    for (int t = 0; t < 64; t++) {
        int s = d ? (63 - t) : t;

        if (t > 0) {
            if (tid < 16) {
                while (__hip_atomic_load(&myflags[tid], __ATOMIC_RELAXED, __HIP_MEMORY_SCOPE_AGENT) <
                       (unsigned)t)
                    __builtin_amdgcn_s_sleep(1);
            }
            __syncthreads();
            // stage h_{t-1} from buf[(t-1)&1]
            unsigned int* src = hsteam + ((t + 1) & 1) * 8192;
#pragma unroll
            for (int i = 0; i < 32; i++) {
                unsigned int v =
                    __hip_atomic_load(&src[i * 256 + tid], __ATOMIC_RELAXED, __HIP_MEMORY_SCOPE_AGENT);
                *(unsigned int*)(hl + i * 1040 + tid * 4) = v;
            }
            __syncthreads();
        }

        // gi: 3 coalesced v4f nontemporal loads
        const float* gp = gi + (((((long)(d * 64 + s)) * 8 + bg) * 16 + cb) * 4 + wave) * 768 + lane * 4;
        v4f gir[3];
#pragma unroll
        for (int g = 0; g < 3; g++)
            gir[g] = __builtin_nontemporal_load((const v4f*)(gp + g * 256));

        // h_prev @ W slice: 48 MFMA (3 gate chains)
        v4f acc[3];
#pragma unroll
        for (int g = 0; g < 3; g++) acc[g] = v4f{0.f, 0.f, 0.f, 0.f};
#pragma unroll
        for (int half = 0; half < 2; half++) {
            v8s af[8];
#pragma unroll
            for (int k8 = 0; k8 < 8; k8++)
                af[k8] = *(const v8s*)(hl + (rg * 16 + l16) * 1040 + (half * 8 + k8) * 64 + q * 16);
#pragma unroll
            for (int k8 = 0; k8 < 8; k8++) {
                int kf = half * 8 + k8;
#pragma unroll
                for (int g = 0; g < 3; g++) {
                    v8s b = *(const v8s*)&Wl[(((long)(g * 2 + jh) * 16 + kf) * 64 + lane) * 8];
                    acc[g] = __builtin_amdgcn_mfma_f32_16x16x32_bf16(af[k8], b, acc[g], 0, 0, 0);
                }
            }
        }

        // combine + write h slice (global share, sc1) + final hout
        unsigned int* dst = hsteam + (t & 1) * 8192;
#pragma unroll
        for (int r = 0; r < 4; r++) {
            int row = rg * 16 + q * 4 + r;
            float rr = sigm(gir[0][r] + bi[0] + acc[0][r] + bh[0]);
            float zz = sigm(gir[1][r] + bi[1] + acc[1][r] + bh[1]);
            float nn = tanh_fast(gir[2][r] + bi[2] + rr * (acc[2][r] + bh[2]));
            float hn = (1.f - zz) * nn + zz * hreg[r];
            hreg[r] = hn;
            unsigned short hv = f2bf(hn);
            hout[((long)(bg * 32 + row) * 64 + s) * 1024 + d * 512 + j] = hv;
            float pv = __shfl_xor(hn, 1);
            if ((l16 & 1) == 0) {
                unsigned int pack = (unsigned int)hv | ((unsigned int)f2bf(pv) << 16);
                __hip_atomic_store(&dst[row * 256 + (j >> 1)], pack, __ATOMIC_RELAXED,
                                   __HIP_MEMORY_SCOPE_AGENT);
            }
        }
        __syncthreads();  // vmcnt(0) drain: all sc1 stores device-visible
        if (tid == 0)
            __hip_atomic_store(&myflags[cb], (unsigned)(t + 1), __ATOMIC_RELEASE,
                               __HIP_MEMORY_SCOPE_AGENT);
    }
}

extern "C" void kernel_launch(void* const* d_in, const int* in_sizes, int n_in,
                              void* d_out, int out_size, void* d_ws, size_t ws_size,
                              hipStream_t stream) {
    const int* slot_ids = (const int*)d_in[0];
    const float* value_embeds = (const float*)d_in[1];
    const float* embed_table = (const float*)d_in[2];
    const float* W_ih_f = (const float*)d_in[3];
    const float* W_hh_f = (const float*)d_in[4];
    const float* b_ih_f = (const float*)d_in[5];
    const float* b_hh_f = (const float*)d_in[6];
    const float* W_ih_b = (const float*)d_in[7];
    const float* W_hh_b = (const float*)d_in[8];
    const float* b_ih_b = (const float*)d_in[9];
    const float* b_hh_b = (const float*)d_in[10];
    const float* W_proj = (const float*)d_in[11];
    float* out = (float*)d_out;
    char* ws = (char*)d_ws;

    // workspace layout (bytes)
    unsigned short* X = (unsigned short*)(ws + 0);              // 16384x1024 bf16 = 33,554,432
    float* gi = (float*)(ws + 33554432);                        // 50,331,648 f32 = 201,326,592
    unsigned short* Wstk = (unsigned short*)(ws + 234881024);   // 3072x1024 bf16 = 6,291,456 (dead after gemm1)
    unsigned short* Wpk = (unsigned short*)(ws + 241172480);    // 2x96x16x64x8 bf16 = 3,145,728
    unsigned short* Wp = (unsigned short*)(ws + 244318208);     // 512x1024 bf16 = 1,048,576
    unsigned short* hout = X;  // alias: X dead after gemm1
    // h-share + flags alias the (dead-after-gemm1) Wstk region
    unsigned int* hshd = (unsigned int*)Wstk;                   // 16*2*8192 dwords = 1 MB
    unsigned int* flags = (unsigned int*)(ws + 234881024 + 1048576);  // 256 dwords

    const int SMEM = 98304 + 33280;  // W slice + staged h = 131,584 B
    hipFuncSetAttribute((const void*)gru_rec, hipFuncAttributeMaxDynamicSharedMemorySize, SMEM);

    cvt_bf16<<<6144, 256, 0, stream>>>(W_ih_f, Wstk, 1536 * 1024);
    cvt_bf16<<<6144, 256, 0, stream>>>(W_ih_b, Wstk + 1536 * 1024, 1536 * 1024);
    repack_whh<<<3072, 256, 0, stream>>>(W_hh_f, Wpk);
    repack_whh<<<3072, 256, 0, stream>>>(W_hh_b, Wpk + 786432);
    cvt_bf16<<<2048, 256, 0, stream>>>(W_proj, Wp, 512 * 1024);
    build_x<<<16384, 256, 0, stream>>>(slot_ids, value_embeds, embed_table, X);

    // gi = X @ [Wih_f; Wih_b]^T  (M=16384, N=3072, K=1024), packed epilogue
    gemm_bt<1><<<dim3(24, 128), 256, 0, stream>>>(X, Wstk, gi, 16384, 3072, 1024);

    // zero flags (after gemm1: aliases Wstk region)
    init_flags<<<1, 256, 0, stream>>>(flags);

    // recurrence: 256 co-resident blocks, W slice in LDS, team flag sync
    gru_rec<<<256, 256, SMEM, stream>>>(gi, Wpk, b_ih_f, b_hh_f, b_ih_b, b_hh_b, hout, hshd, flags);

    // out = hcat @ W_proj^T   (M=16384, N=512, K=1024)
    gemm_bt<0><<<dim3(4, 128), 256, 0, stream>>>(hout, Wp, out, 16384, 512, 1024);
}